// Round 1
// baseline (28.758 us; speedup 1.0000x reference)
//
#include <hip/hip_runtime.h>

// MaxIndexLinearTraining: per-group (q=4) softmax then weighted sum with [1,2,3,4].
// Input: (4096, 8192) f32 -> viewed as 8M groups of 4 consecutive floats.
// Output: (4096, 2048) f32 = 8,388,608 elements, one per group.
// Purely memory-bound: 16B read + 4B write per output.

__global__ __launch_bounds__(256) void soft_argmax_q4_kernel(
    const float4* __restrict__ in,   // one float4 per group
    float* __restrict__ out,
    int n_groups)
{
    int idx    = blockIdx.x * blockDim.x + threadIdx.x;
    int stride = gridDim.x * blockDim.x;
    for (int g = idx; g < n_groups; g += stride) {
        float4 v = in[g];
        // max for numerical stability (cheap; compiler may fuse to v_max3)
        float m  = fmaxf(fmaxf(v.x, v.y), fmaxf(v.z, v.w));
        float e0 = __expf(v.x - m);
        float e1 = __expf(v.y - m);
        float e2 = __expf(v.z - m);
        float e3 = __expf(v.w - m);
        float denom = e0 + e1 + e2 + e3;
        float num   = fmaf(4.f, e3, fmaf(3.f, e2, fmaf(2.f, e1, e0)));
        out[g] = num / denom;
    }
}

extern "C" void kernel_launch(void* const* d_in, const int* in_sizes, int n_in,
                              void* d_out, int out_size, void* d_ws, size_t ws_size,
                              hipStream_t stream) {
    (void)n_in; (void)d_ws; (void)ws_size;
    const float4* in = (const float4*)d_in[0];
    float* out = (float*)d_out;

    const int n_groups = out_size;                 // 4096 * 2048 = 8,388,608
    const int block = 256;
    int grid = (n_groups + block - 1) / block;
    if (grid > 4096) grid = 4096;                  // grid-stride the rest

    soft_argmax_q4_kernel<<<grid, block, 0, stream>>>(in, out, n_groups);
}